// Round 2
// baseline (1098.470 us; speedup 1.0000x reference)
//
#include <hip/hip_runtime.h>
#include <hip/hip_bf16.h>

// Problem constants (B,T,D,H,E,TOP_K) = (4,2048,1024,4096,8,2)
#define NTOK 8192            // B*T
#define DDIM 1024
#define HDIM 4096
#define NEXP 8
#define NSLOT (NTOK * 2)     // exactly 16384 slots (each token -> 2 experts)
#define MAXTILES 136         // sum_e ceil(cnt_e/128) <= 8 + 16384/128 = 136

#define BM 128
#define BN 128
#define BK 32

typedef __attribute__((ext_vector_type(8))) short bfrag;   // 8 bf16 (4 VGPRs)
typedef __attribute__((ext_vector_type(4))) float f32x4;

__device__ __forceinline__ unsigned short f2bf(float f) {
  union { __hip_bfloat16 h; unsigned short u; } cv;
  cv.h = __float2bfloat16(f);
  return cv.u;
}

// async global->LDS, 16B per lane; LDS dest is wave-uniform base + lane*16
__device__ __forceinline__ void glds16(const unsigned short* g, unsigned short* l) {
  __builtin_amdgcn_global_load_lds(
      (const __attribute__((address_space(1))) unsigned int*)g,
      (__attribute__((address_space(3))) unsigned int*)l, 16, 0, 0);
}

// ---------------- ws layout: fixed part (bytes) ----------------
#define WS_COUNTS      0UL
#define WS_CURSORS     256UL
#define WS_OFFSETS     512UL
#define WS_TABLE       1024UL        // 136*16 = 2176 -> ends 3200
#define WS_TOKE        4096UL        // 64 KB
#define WS_TOKG        69632UL       // 64 KB
#define WS_SLOT_TOKEN  135168UL      // 64 KB
#define WS_SLOT_GATE   200704UL      // 64 KB
#define WS_XB          266240UL      // NTOK*DDIM bf16 = 16 MiB
#define WS_DYN         17043456UL    // dynamic region: W1Tc | W2Tc | hbuf
// dynamic cost per H-chunk element HC: W1Tc 16384*HC + W2Tc 16384*HC + hbuf 32768*HC

// ---------------- x fp32 -> bf16 ----------------
__global__ void cvt_x_kernel(const float* __restrict__ x,
                             unsigned short* __restrict__ xb, int n4) {
  int i = blockIdx.x * blockDim.x + threadIdx.x;
  if (i >= n4) return;
  float4 v = reinterpret_cast<const float4*>(x)[i];
  ushort4 u;
  u.x = f2bf(v.x); u.y = f2bf(v.y); u.z = f2bf(v.z); u.w = f2bf(v.w);
  reinterpret_cast<ushort4*>(xb)[i] = u;
}

// ---- batched transpose+convert: out[e][c][r] = bf16(in[e][r][c]), sub-rect ----
// in is pre-offset to (row0,col0) of expert 0; in[e*in_estride + r*in_rstride + c]
__global__ void transpose_cvt_kernel(const float* __restrict__ in,
                                     unsigned short* __restrict__ out,
                                     int Rsub, int in_rstride,
                                     size_t in_estride, size_t out_estride) {
  __shared__ float tile[32][33];
  int b = blockIdx.z;
  int r0 = blockIdx.y * 32, c0 = blockIdx.x * 32;
  const float* src = in + (size_t)b * in_estride;
  unsigned short* dst = out + (size_t)b * out_estride;
  int tc = threadIdx.x & 31, tr = threadIdx.x >> 5;   // 32 cols x 8 rows per pass
#pragma unroll
  for (int i = 0; i < 4; i++)
    tile[tr + 8 * i][tc] = src[(size_t)(r0 + tr + 8 * i) * in_rstride + (c0 + tc)];
  __syncthreads();
#pragma unroll
  for (int i = 0; i < 4; i++)
    dst[(size_t)(c0 + tr + 8 * i) * Rsub + (r0 + tc)] = f2bf(tile[tc][tr + 8 * i]);
}

// ---------------- fp32 router: noisy top-2 + gates ----------------
__global__ void router_kernel(const float* __restrict__ x,
                              const float* __restrict__ noise,
                              const float* __restrict__ Wr,
                              const float* __restrict__ Wn,
                              int* __restrict__ counts,
                              int* __restrict__ tok_e,
                              float* __restrict__ tok_g) {
  int tok = (int)((blockIdx.x * (size_t)blockDim.x + threadIdx.x) >> 6);
  int lane = threadIdx.x & 63;
  if (tok >= NTOK) return;
  const float* xrow = x + (size_t)tok * DDIM;

  float accR[NEXP], accN[NEXP];
#pragma unroll
  for (int e = 0; e < NEXP; e++) { accR[e] = 0.f; accN[e] = 0.f; }

  for (int j = 0; j < DDIM / 64; j++) {
    int d = lane + 64 * j;
    float xv = xrow[d];
#pragma unroll
    for (int e = 0; e < NEXP; e++) {
      accR[e] = fmaf(xv, Wr[e * DDIM + d], accR[e]);
      accN[e] = fmaf(xv, Wn[e * DDIM + d], accN[e]);
    }
  }
#pragma unroll
  for (int e = 0; e < NEXP; e++) {
    float r = accR[e], n = accN[e];
    for (int s = 32; s > 0; s >>= 1) { r += __shfl_xor(r, s); n += __shfl_xor(n, s); }
    accR[e] = r; accN[e] = n;
  }
  if (lane == 0) {
    float noisy[NEXP];
#pragma unroll
    for (int e = 0; e < NEXP; e++) {
      float nl = accN[e];
      float sp = (nl > 15.f) ? nl : log1pf(expf(nl));   // softplus
      noisy[e] = accR[e] + noise[(size_t)tok * NEXP + e] * sp;
    }
    int i0 = 0;
#pragma unroll
    for (int e = 1; e < NEXP; e++) if (noisy[e] > noisy[i0]) i0 = e;
    int i1 = (i0 == 0) ? 1 : 0;
#pragma unroll
    for (int e = 0; e < NEXP; e++)
      if (e != i0 && noisy[e] > noisy[i1]) i1 = e;
    float ex = expf(noisy[i1] - noisy[i0]);    // <= 1
    float denom = 1.f + ex;
    tok_e[tok * 2 + 0] = i0; tok_e[tok * 2 + 1] = i1;
    tok_g[tok * 2 + 0] = 1.f / denom; tok_g[tok * 2 + 1] = ex / denom;
    atomicAdd(&counts[i0], 1);
    atomicAdd(&counts[i1], 1);
  }
}

// ---------------- offsets + tile table (single block) ----------------
__global__ void build_meta_kernel(const int* __restrict__ counts,
                                  int* __restrict__ offsets,
                                  int* __restrict__ cursors,
                                  int4* __restrict__ table) {
  if (threadIdx.x == 0) {
    int off = 0, nt = 0;
    for (int e = 0; e < NEXP; e++) {
      offsets[e] = off;
      cursors[e] = 0;
      int c = counts[e];
      for (int r = 0; r < c; r += BM) {
        int rows = c - r; if (rows > BM) rows = BM;
        table[nt++] = make_int4(e, off + r, rows, 0);
      }
      off += c;
    }
    offsets[NEXP] = off;
    for (; nt < MAXTILES; nt++) table[nt] = make_int4(-1, 0, 0, 0);
  }
}

// ---------------- compact slot assignment ----------------
__global__ void assign_slots_kernel(const int* __restrict__ tok_e,
                                    const float* __restrict__ tok_g,
                                    const int* __restrict__ offsets,
                                    int* __restrict__ cursors,
                                    int* __restrict__ slot_token,
                                    float* __restrict__ slot_gate) {
  int t = blockIdx.x * blockDim.x + threadIdx.x;
  if (t >= NTOK) return;
#pragma unroll
  for (int k = 0; k < 2; k++) {
    int e = tok_e[t * 2 + k];
    int pos = atomicAdd(&cursors[e], 1);
    int s = offsets[e] + pos;
    slot_token[s] = t;
    slot_gate[s] = tok_g[t * 2 + k];
  }
}

// ---------------- grouped GEMM (m97 structure: global_load_lds + linear LDS) ----
// MODE 0: hchunk[slot][0..hcur) = relu(x[tok] @ W1c[e])^2   A=xb gathered, B=W1Tc
// MODE 1: out[tok][:] += gate * (hchunk[slot] @ W2c[e])     A=hchunk,      B=W2Tc
template <int MODE>
__global__ __launch_bounds__(256) void moe_gemm_kernel(
    const unsigned short* __restrict__ Amat,
    const unsigned short* __restrict__ Bmat,
    const int4* __restrict__ table,
    const int* __restrict__ slot_token,
    const float* __restrict__ slot_gate,
    unsigned short* __restrict__ hout,
    float* __restrict__ oout,
    int kd, int astride, int b_rstride, size_t b_estride, int hcur) {
  int4 te = table[blockIdx.y];
  int e = te.x;
  if (e < 0) return;
  int slot_base = te.y;
  int rows = te.z;
  int col0 = blockIdx.x * BN;

  __shared__ __align__(16) unsigned short As[BM][BK];   // 8 KB, linear (glds dest)
  __shared__ __align__(16) unsigned short Bs[BN][BK];   // 8 KB

  int tid = threadIdx.x;
  int lane = tid & 63, wid = tid >> 6;
  int wr = wid >> 1, wc = wid & 1;       // 2x2 waves -> 64x64 each

  // glds staging geometry: inst (wid,j) covers 16 rows; lane l -> row +(l>>2), 8 elems at (l&3)*8
  int r0 = (wid * 2 + 0) * 16 + (lane >> 2);
  int r1 = (wid * 2 + 1) * 16 + (lane >> 2);
  int koff = (lane & 3) * 8;

  int s0 = slot_base + r0; if (s0 > NSLOT - 1) s0 = NSLOT - 1;
  int s1 = slot_base + r1; if (s1 > NSLOT - 1) s1 = NSLOT - 1;
  size_t arow0, arow1;
  if (MODE == 0) { arow0 = (size_t)slot_token[s0] * astride; arow1 = (size_t)slot_token[s1] * astride; }
  else           { arow0 = (size_t)s0 * astride;             arow1 = (size_t)s1 * astride; }
  const unsigned short* ag0 = Amat + arow0 + koff;
  const unsigned short* ag1 = Amat + arow1 + koff;
  const unsigned short* bbase = Bmat + (size_t)e * b_estride;
  const unsigned short* bg0 = bbase + (size_t)(col0 + r0) * b_rstride + koff;
  const unsigned short* bg1 = bbase + (size_t)(col0 + r1) * b_rstride + koff;

  unsigned short* la0 = &As[(wid * 2 + 0) * 16][0];   // wave-uniform LDS bases
  unsigned short* la1 = &As[(wid * 2 + 1) * 16][0];
  unsigned short* lb0 = &Bs[(wid * 2 + 0) * 16][0];
  unsigned short* lb1 = &Bs[(wid * 2 + 1) * 16][0];

  f32x4 acc[4][4];
#pragma unroll
  for (int m = 0; m < 4; m++)
#pragma unroll
    for (int n = 0; n < 4; n++) acc[m][n] = (f32x4)(0.f);

  const int gk = (lane >> 4) * 8;   // k-offset within BK for MFMA fragment
  const int rl = lane & 15;

  for (int k0 = 0; k0 < kd; k0 += BK) {
    __syncthreads();                 // previous iter's LDS reads complete
    glds16(ag0 + k0, la0);
    glds16(ag1 + k0, la1);
    glds16(bg0 + k0, lb0);
    glds16(bg1 + k0, lb1);
    __syncthreads();                 // vmcnt(0) drained by compiler before barrier

    bfrag af[4], bfr[4];
#pragma unroll
    for (int m = 0; m < 4; m++)
      af[m] = *reinterpret_cast<const bfrag*>(&As[wr * 64 + m * 16 + rl][gk]);
#pragma unroll
    for (int n = 0; n < 4; n++)
      bfr[n] = *reinterpret_cast<const bfrag*>(&Bs[wc * 64 + n * 16 + rl][gk]);
#pragma unroll
    for (int m = 0; m < 4; m++)
#pragma unroll
      for (int n = 0; n < 4; n++)
        acc[m][n] = __builtin_amdgcn_mfma_f32_16x16x32_bf16(af[m], bfr[n], acc[m][n], 0, 0, 0);
  }

  const int gi = lane >> 4, cl = lane & 15;
  if (MODE == 0) {
#pragma unroll
    for (int m = 0; m < 4; m++) {
#pragma unroll
      for (int rr = 0; rr < 4; rr++) {
        int row = wr * 64 + m * 16 + gi * 4 + rr;
        if (row < rows) {
          size_t base = (size_t)(slot_base + row) * hcur;
#pragma unroll
          for (int n = 0; n < 4; n++) {
            int col = col0 + wc * 64 + n * 16 + cl;
            float v = fmaxf(acc[m][n][rr], 0.f);
            hout[base + col] = f2bf(v * v);
          }
        }
      }
    }
  } else {
#pragma unroll
    for (int m = 0; m < 4; m++) {
#pragma unroll
      for (int rr = 0; rr < 4; rr++) {
        int row = wr * 64 + m * 16 + gi * 4 + rr;
        if (row < rows) {
          int slot = slot_base + row;
          int tok = slot_token[slot];
          float gv = slot_gate[slot];
          float* obase = oout + (size_t)tok * DDIM;
#pragma unroll
          for (int n = 0; n < 4; n++) {
            int col = col0 + wc * 64 + n * 16 + cl;
            atomicAdd(&obase[col], gv * acc[m][n][rr]);
          }
        }
      }
    }
  }
}

extern "C" void kernel_launch(void* const* d_in, const int* in_sizes, int n_in,
                              void* d_out, int out_size, void* d_ws, size_t ws_size,
                              hipStream_t stream) {
  const float* x     = (const float*)d_in[0];
  const float* noise = (const float*)d_in[1];
  const float* Wr    = (const float*)d_in[2];
  const float* Wn    = (const float*)d_in[3];
  const float* W1    = (const float*)d_in[4];
  const float* W2    = (const float*)d_in[5];
  float* out = (float*)d_out;
  char* ws = (char*)d_ws;

  int*   counts     = (int*)(ws + WS_COUNTS);
  int*   cursors    = (int*)(ws + WS_CURSORS);
  int*   offsets    = (int*)(ws + WS_OFFSETS);
  int4*  table      = (int4*)(ws + WS_TABLE);
  int*   tok_e      = (int*)(ws + WS_TOKE);
  float* tok_g      = (float*)(ws + WS_TOKG);
  int*   slot_token = (int*)(ws + WS_SLOT_TOKEN);
  float* slot_gate  = (float*)(ws + WS_SLOT_GATE);
  unsigned short* xb = (unsigned short*)(ws + WS_XB);

  (void)in_sizes; (void)n_in;

  // Pick largest H-chunk (divisor of HDIM) whose dynamic buffers fit ws_size.
  // dyn bytes = (W1Tc + W2Tc + hbuf) = 16384*HC + 16384*HC + 32768*HC = 65536*HC
  int HC = 128;
  for (int cand = HDIM; cand >= 128; cand >>= 1) {
    if (WS_DYN + 65536ULL * (unsigned long long)cand <= (unsigned long long)ws_size) { HC = cand; break; }
  }
  unsigned short* W1Tc = (unsigned short*)(ws + WS_DYN);
  unsigned short* W2Tc = W1Tc + (size_t)NEXP * HC * DDIM;
  unsigned short* hbuf = W2Tc + (size_t)NEXP * DDIM * HC;

  // zero expert counts + output accumulator
  hipMemsetAsync(ws + WS_COUNTS, 0, 64, stream);
  hipMemsetAsync(out, 0, (size_t)out_size * sizeof(float), stream);

  // x -> bf16
  {
    int n4 = NTOK * DDIM / 4;
    cvt_x_kernel<<<(n4 + 255) / 256, 256, 0, stream>>>(x, xb, n4);
  }

  // router (fp32 exact) + metadata
  router_kernel<<<NTOK * 64 / 256, 256, 0, stream>>>(x, noise, Wr, Wn, counts, tok_e, tok_g);
  build_meta_kernel<<<1, 64, 0, stream>>>(counts, offsets, cursors, table);
  assign_slots_kernel<<<NTOK / 256, 256, 0, stream>>>(tok_e, tok_g, offsets, cursors,
                                                      slot_token, slot_gate);

  int nc = HDIM / HC;
  for (int c = 0; c < nc; ++c) {
    size_t hc0 = (size_t)c * HC;
    // W1 chunk [E][D][hc0:hc0+HC] -> W1Tc [E][HC][D]
    transpose_cvt_kernel<<<dim3(HC / 32, DDIM / 32, NEXP), 256, 0, stream>>>(
        W1 + hc0, W1Tc, DDIM, HDIM, (size_t)DDIM * HDIM, (size_t)HC * DDIM);
    // W2 chunk [E][hc0:hc0+HC][D] -> W2Tc [E][D][HC]
    transpose_cvt_kernel<<<dim3(DDIM / 32, HC / 32, NEXP), 256, 0, stream>>>(
        W2 + hc0 * DDIM, W2Tc, HC, DDIM, (size_t)HDIM * DDIM, (size_t)DDIM * HC);

    // fc1: hbuf[slot][0..HC) = relu(x @ W1c)^2
    moe_gemm_kernel<0><<<dim3(HC / BN, MAXTILES), 256, 0, stream>>>(
        xb, W1Tc, table, slot_token, slot_gate, hbuf, nullptr,
        /*kd*/DDIM, /*astride*/DDIM, /*b_rstride*/DDIM, /*b_estride*/(size_t)HC * DDIM, /*hcur*/HC);
    // fc2: out += gate * (hbuf @ W2c)
    moe_gemm_kernel<1><<<dim3(DDIM / BN, MAXTILES), 256, 0, stream>>>(
        hbuf, W2Tc, table, slot_token, slot_gate, nullptr, out,
        /*kd*/HC, /*astride*/HC, /*b_rstride*/HC, /*b_estride*/(size_t)DDIM * HC, /*hcur*/HC);
  }
}

// Round 3
// 1076.779 us; speedup vs baseline: 1.0201x; 1.0201x over previous
//
#include <hip/hip_runtime.h>
#include <hip/hip_bf16.h>

// Problem constants (B,T,D,H,E,TOP_K) = (4,2048,1024,4096,8,2)
#define NTOK 8192            // B*T
#define DDIM 1024
#define HDIM 4096
#define NEXP 8
#define NSLOT (NTOK * 2)     // exactly 16384 slots
#define MAXTILES 136         // sum_e ceil(cnt_e/128) <= 8 + 16384/128 = 136

#define BM 128
#define BN 128
#define BK 32

typedef __attribute__((ext_vector_type(8))) short bfrag;   // 8 bf16 (4 VGPRs)
typedef __attribute__((ext_vector_type(4))) float f32x4;

__device__ __forceinline__ unsigned short f2bf(float f) {
  union { __hip_bfloat16 h; unsigned short u; } cv;
  cv.h = __float2bfloat16(f);
  return cv.u;
}

// async global->LDS, 16B per lane; LDS dest is wave-uniform base + lane*16
__device__ __forceinline__ void glds16(const unsigned short* g, unsigned short* l) {
  __builtin_amdgcn_global_load_lds(
      (const __attribute__((address_space(1))) unsigned int*)g,
      (__attribute__((address_space(3))) unsigned int*)l, 16, 0, 0);
}

// ---------------- ws layout: fixed part (bytes) ----------------
#define WS_COUNTS      0UL
#define WS_CURSORS     256UL
#define WS_OFFSETS     512UL
#define WS_TABLE       1024UL
#define WS_TOKE        4096UL
#define WS_TOKG        69632UL
#define WS_SLOT_TOKEN  135168UL
#define WS_SLOT_GATE   200704UL
#define WS_XB          266240UL      // NTOK*DDIM bf16 = 16 MiB
#define WS_DYN         17043456UL    // W1Tc | W2Tc | hbuf ; 65536*HC bytes

// ---------------- x fp32 -> bf16 ----------------
__global__ void cvt_x_kernel(const float* __restrict__ x,
                             unsigned short* __restrict__ xb, int n4) {
  int i = blockIdx.x * blockDim.x + threadIdx.x;
  if (i >= n4) return;
  float4 v = reinterpret_cast<const float4*>(x)[i];
  ushort4 u;
  u.x = f2bf(v.x); u.y = f2bf(v.y); u.z = f2bf(v.z); u.w = f2bf(v.w);
  reinterpret_cast<ushort4*>(xb)[i] = u;
}

// ---- transpose+convert: out[b][c][r] = bf16(in[b][r][c]), 64x64 tiles ----
// in pre-offset to (0, col0_global); strides passed explicitly.
__global__ __launch_bounds__(256) void transpose_cvt_kernel(
    const float* __restrict__ in, unsigned short* __restrict__ out,
    int Rsub, int in_rstride, size_t in_estride, size_t out_estride) {
  __shared__ float tile[64][65];
  int b = blockIdx.z;
  int r0 = blockIdx.y * 64, c0 = blockIdx.x * 64;
  const float* src = in + (size_t)b * in_estride + (size_t)r0 * in_rstride + c0;
  unsigned short* dst = out + (size_t)b * out_estride + (size_t)c0 * Rsub + r0;
  int t = threadIdx.x;
  int lr = t >> 4;            // 0..15
  int lc4 = (t & 15) * 4;     // 0,4,...,60
#pragma unroll
  for (int p = 0; p < 4; p++) {
    int r = lr + p * 16;
    float4 v = *reinterpret_cast<const float4*>(src + (size_t)r * in_rstride + lc4);
    tile[r][lc4 + 0] = v.x; tile[r][lc4 + 1] = v.y;
    tile[r][lc4 + 2] = v.z; tile[r][lc4 + 3] = v.w;
  }
  __syncthreads();
#pragma unroll
  for (int p = 0; p < 4; p++) {
    int c = lr + p * 16;      // out row (= in col)
    ushort4 u;
    u.x = f2bf(tile[lc4 + 0][c]);
    u.y = f2bf(tile[lc4 + 1][c]);
    u.z = f2bf(tile[lc4 + 2][c]);
    u.w = f2bf(tile[lc4 + 3][c]);
    *reinterpret_cast<ushort4*>(dst + (size_t)c * Rsub + lc4) = u;
  }
}

// ---------------- fp32 router: noisy top-2 + gates ----------------
__global__ void router_kernel(const float* __restrict__ x,
                              const float* __restrict__ noise,
                              const float* __restrict__ Wr,
                              const float* __restrict__ Wn,
                              int* __restrict__ counts,
                              int* __restrict__ tok_e,
                              float* __restrict__ tok_g) {
  int tok = (int)((blockIdx.x * (size_t)blockDim.x + threadIdx.x) >> 6);
  int lane = threadIdx.x & 63;
  if (tok >= NTOK) return;
  const float* xrow = x + (size_t)tok * DDIM;

  float accR[NEXP], accN[NEXP];
#pragma unroll
  for (int e = 0; e < NEXP; e++) { accR[e] = 0.f; accN[e] = 0.f; }

  for (int j = 0; j < DDIM / 64; j++) {
    int d = lane + 64 * j;
    float xv = xrow[d];
#pragma unroll
    for (int e = 0; e < NEXP; e++) {
      accR[e] = fmaf(xv, Wr[e * DDIM + d], accR[e]);
      accN[e] = fmaf(xv, Wn[e * DDIM + d], accN[e]);
    }
  }
#pragma unroll
  for (int e = 0; e < NEXP; e++) {
    float r = accR[e], n = accN[e];
    for (int s = 32; s > 0; s >>= 1) { r += __shfl_xor(r, s); n += __shfl_xor(n, s); }
    accR[e] = r; accN[e] = n;
  }
  if (lane == 0) {
    float noisy[NEXP];
#pragma unroll
    for (int e = 0; e < NEXP; e++) {
      float nl = accN[e];
      float sp = (nl > 15.f) ? nl : log1pf(expf(nl));   // softplus
      noisy[e] = accR[e] + noise[(size_t)tok * NEXP + e] * sp;
    }
    int i0 = 0;
#pragma unroll
    for (int e = 1; e < NEXP; e++) if (noisy[e] > noisy[i0]) i0 = e;
    int i1 = (i0 == 0) ? 1 : 0;
#pragma unroll
    for (int e = 0; e < NEXP; e++)
      if (e != i0 && noisy[e] > noisy[i1]) i1 = e;
    float ex = expf(noisy[i1] - noisy[i0]);    // <= 1
    float denom = 1.f + ex;
    tok_e[tok * 2 + 0] = i0; tok_e[tok * 2 + 1] = i1;
    tok_g[tok * 2 + 0] = 1.f / denom; tok_g[tok * 2 + 1] = ex / denom;
    atomicAdd(&counts[i0], 1);
    atomicAdd(&counts[i1], 1);
  }
}

// ---------------- offsets + tile table (single block) ----------------
__global__ void build_meta_kernel(const int* __restrict__ counts,
                                  int* __restrict__ offsets,
                                  int* __restrict__ cursors,
                                  int4* __restrict__ table) {
  if (threadIdx.x == 0) {
    int off = 0, nt = 0;
    for (int e = 0; e < NEXP; e++) {
      offsets[e] = off;
      cursors[e] = 0;
      int c = counts[e];
      for (int r = 0; r < c; r += BM) {
        int rows = c - r; if (rows > BM) rows = BM;
        table[nt++] = make_int4(e, off + r, rows, 0);
      }
      off += c;
    }
    offsets[NEXP] = off;
    for (; nt < MAXTILES; nt++) table[nt] = make_int4(-1, 0, 0, 0);
  }
}

// ---------------- compact slot assignment ----------------
__global__ void assign_slots_kernel(const int* __restrict__ tok_e,
                                    const float* __restrict__ tok_g,
                                    const int* __restrict__ offsets,
                                    int* __restrict__ cursors,
                                    int* __restrict__ slot_token,
                                    float* __restrict__ slot_gate) {
  int t = blockIdx.x * blockDim.x + threadIdx.x;
  if (t >= NTOK) return;
#pragma unroll
  for (int k = 0; k < 2; k++) {
    int e = tok_e[t * 2 + k];
    int pos = atomicAdd(&cursors[e], 1);
    int s = offsets[e] + pos;
    slot_token[s] = t;
    slot_gate[s] = tok_g[t * 2 + k];
  }
}

// ---------------- grouped GEMM: dbuf LDS + single barrier per K-step ----
// MODE 0: hchunk[slot][:] = relu(x[tok] @ W1c[e])^2   A=xb gathered, B=W1Tc
// MODE 1: out[tok][:]   += gate * (hchunk[slot] @ W2c[e])
template <int MODE>
__global__ __launch_bounds__(256) void moe_gemm_kernel(
    const unsigned short* __restrict__ Amat,
    const unsigned short* __restrict__ Bmat,
    const int4* __restrict__ table,
    const int* __restrict__ slot_token,
    const float* __restrict__ slot_gate,
    unsigned short* __restrict__ hout,
    float* __restrict__ oout,
    int kd, int astride, int b_rstride, size_t b_estride, int hcur) {
  int4 te = table[blockIdx.y];
  int e = te.x;
  if (e < 0) return;
  int slot_base = te.y;
  int rows = te.z;
  int col0 = blockIdx.x * BN;

  __shared__ __align__(16) unsigned short As[2][BM][BK];   // 16 KB
  __shared__ __align__(16) unsigned short Bs[2][BM][BK];   // 16 KB

  int tid = threadIdx.x;
  int lane = tid & 63, wid = tid >> 6;
  int wr = wid >> 1, wc = wid & 1;       // 2x2 waves -> 64x64 each

  // glds staging: each wave stages 2x16 rows of A and B; lane l -> row +(l>>2),
  // 8 bf16 at k-offset (l&3)*8
  int r0 = wid * 32 + (lane >> 2);
  int r1 = wid * 32 + 16 + (lane >> 2);
  int koff = (lane & 3) * 8;

  int s0 = slot_base + r0; if (s0 > NSLOT - 1) s0 = NSLOT - 1;
  int s1 = slot_base + r1; if (s1 > NSLOT - 1) s1 = NSLOT - 1;
  size_t arow0, arow1;
  if (MODE == 0) { arow0 = (size_t)slot_token[s0] * astride; arow1 = (size_t)slot_token[s1] * astride; }
  else           { arow0 = (size_t)s0 * astride;             arow1 = (size_t)s1 * astride; }
  const unsigned short* ag0 = Amat + arow0 + koff;
  const unsigned short* ag1 = Amat + arow1 + koff;
  const unsigned short* bbase = Bmat + (size_t)e * b_estride;
  const unsigned short* bg0 = bbase + (size_t)(col0 + r0) * b_rstride + koff;
  const unsigned short* bg1 = bbase + (size_t)(col0 + r1) * b_rstride + koff;

  f32x4 acc[4][4];
#pragma unroll
  for (int m = 0; m < 4; m++)
#pragma unroll
    for (int n = 0; n < 4; n++) acc[m][n] = (f32x4)(0.f);

  const int gk = (lane >> 4) * 8;   // k-offset within BK for MFMA fragment
  const int rl = lane & 15;

  int nt = kd / BK;
  // prologue: stage K-tile 0 into buf 0
  glds16(ag0, &As[0][wid * 32][0]);
  glds16(ag1, &As[0][wid * 32 + 16][0]);
  glds16(bg0, &Bs[0][wid * 32][0]);
  glds16(bg1, &Bs[0][wid * 32 + 16][0]);
  __syncthreads();                  // vmcnt(0) drained by compiler

  int cur = 0;
  for (int t = 0; t < nt; ++t) {
    // issue next K-tile's async loads into the other buffer
    if (t + 1 < nt) {
      int nk = (t + 1) * BK;
      int nxt = cur ^ 1;
      glds16(ag0 + nk, &As[nxt][wid * 32][0]);
      glds16(ag1 + nk, &As[nxt][wid * 32 + 16][0]);
      glds16(bg0 + nk, &Bs[nxt][wid * 32][0]);
      glds16(bg1 + nk, &Bs[nxt][wid * 32 + 16][0]);
    }
    // compute on current buffer
    bfrag af[4], bfr[4];
#pragma unroll
    for (int m = 0; m < 4; m++)
      af[m] = *reinterpret_cast<const bfrag*>(&As[cur][wr * 64 + m * 16 + rl][gk]);
#pragma unroll
    for (int n = 0; n < 4; n++)
      bfr[n] = *reinterpret_cast<const bfrag*>(&Bs[cur][wc * 64 + n * 16 + rl][gk]);
#pragma unroll
    for (int m = 0; m < 4; m++)
#pragma unroll
      for (int n = 0; n < 4; n++)
        acc[m][n] = __builtin_amdgcn_mfma_f32_16x16x32_bf16(af[m], bfr[n], acc[m][n], 0, 0, 0);
    __syncthreads();                // drains prefetch (has had full MFMA phase)
    cur ^= 1;
  }

  const int gi = lane >> 4, cl = lane & 15;
  if (MODE == 0) {
#pragma unroll
    for (int m = 0; m < 4; m++) {
#pragma unroll
      for (int rr = 0; rr < 4; rr++) {
        int row = wr * 64 + m * 16 + gi * 4 + rr;
        if (row < rows) {
          size_t base = (size_t)(slot_base + row) * hcur;
#pragma unroll
          for (int n = 0; n < 4; n++) {
            int col = col0 + wc * 64 + n * 16 + cl;
            float v = fmaxf(acc[m][n][rr], 0.f);
            hout[base + col] = f2bf(v * v);
          }
        }
      }
    }
  } else {
#pragma unroll
    for (int m = 0; m < 4; m++) {
#pragma unroll
      for (int rr = 0; rr < 4; rr++) {
        int row = wr * 64 + m * 16 + gi * 4 + rr;
        if (row < rows) {
          int slot = slot_base + row;
          int tok = slot_token[slot];
          float gv = slot_gate[slot];
          float* obase = oout + (size_t)tok * DDIM;
#pragma unroll
          for (int n = 0; n < 4; n++) {
            int col = col0 + wc * 64 + n * 16 + cl;
            atomicAdd(&obase[col], gv * acc[m][n][rr]);
          }
        }
      }
    }
  }
}

extern "C" void kernel_launch(void* const* d_in, const int* in_sizes, int n_in,
                              void* d_out, int out_size, void* d_ws, size_t ws_size,
                              hipStream_t stream) {
  const float* x     = (const float*)d_in[0];
  const float* noise = (const float*)d_in[1];
  const float* Wr    = (const float*)d_in[2];
  const float* Wn    = (const float*)d_in[3];
  const float* W1    = (const float*)d_in[4];
  const float* W2    = (const float*)d_in[5];
  float* out = (float*)d_out;
  char* ws = (char*)d_ws;

  int*   counts     = (int*)(ws + WS_COUNTS);
  int*   cursors    = (int*)(ws + WS_CURSORS);
  int*   offsets    = (int*)(ws + WS_OFFSETS);
  int4*  table      = (int4*)(ws + WS_TABLE);
  int*   tok_e      = (int*)(ws + WS_TOKE);
  float* tok_g      = (float*)(ws + WS_TOKG);
  int*   slot_token = (int*)(ws + WS_SLOT_TOKEN);
  float* slot_gate  = (float*)(ws + WS_SLOT_GATE);
  unsigned short* xb = (unsigned short*)(ws + WS_XB);

  (void)in_sizes; (void)n_in;

  // Largest H-chunk (divisor of HDIM) fitting ws: dyn = 65536*HC bytes
  int HC = 128;
  for (int cand = HDIM; cand >= 128; cand >>= 1) {
    if (WS_DYN + 65536ULL * (unsigned long long)cand <= (unsigned long long)ws_size) { HC = cand; break; }
  }
  unsigned short* W1Tc = (unsigned short*)(ws + WS_DYN);
  unsigned short* W2Tc = W1Tc + (size_t)NEXP * HC * DDIM;
  unsigned short* hbuf = W2Tc + (size_t)NEXP * DDIM * HC;

  hipMemsetAsync(ws + WS_COUNTS, 0, 64, stream);
  hipMemsetAsync(out, 0, (size_t)out_size * sizeof(float), stream);

  {
    int n4 = NTOK * DDIM / 4;
    cvt_x_kernel<<<(n4 + 255) / 256, 256, 0, stream>>>(x, xb, n4);
  }

  router_kernel<<<NTOK * 64 / 256, 256, 0, stream>>>(x, noise, Wr, Wn, counts, tok_e, tok_g);
  build_meta_kernel<<<1, 64, 0, stream>>>(counts, offsets, cursors, table);
  assign_slots_kernel<<<NTOK / 256, 256, 0, stream>>>(tok_e, tok_g, offsets, cursors,
                                                      slot_token, slot_gate);

  int nc = HDIM / HC;
  for (int c = 0; c < nc; ++c) {
    size_t hc0 = (size_t)c * HC;
    // W1 chunk [E][D][hc0:+HC] -> W1Tc [E][HC][D]
    transpose_cvt_kernel<<<dim3(HC / 64, DDIM / 64, NEXP), 256, 0, stream>>>(
        W1 + hc0, W1Tc, DDIM, HDIM, (size_t)DDIM * HDIM, (size_t)HC * DDIM);
    // W2 chunk [E][hc0:+HC][D] -> W2Tc [E][D][HC]
    transpose_cvt_kernel<<<dim3(DDIM / 64, HC / 64, NEXP), 256, 0, stream>>>(
        W2 + hc0 * DDIM, W2Tc, HC, DDIM, (size_t)HDIM * DDIM, (size_t)DDIM * HC);

    // fc1: hbuf[slot][0..HC) = relu(x @ W1c)^2
    moe_gemm_kernel<0><<<dim3(HC / BN, MAXTILES), 256, 0, stream>>>(
        xb, W1Tc, table, slot_token, slot_gate, hbuf, nullptr,
        DDIM, DDIM, DDIM, (size_t)HC * DDIM, HC);
    // fc2: out += gate * (hbuf @ W2c)
    moe_gemm_kernel<1><<<dim3(DDIM / BN, MAXTILES), 256, 0, stream>>>(
        hbuf, W2Tc, table, slot_token, slot_gate, nullptr, out,
        HC, HC, HC, (size_t)DDIM * HC, HC);
  }
}